// Round 2
// baseline (36.316 us; speedup 1.0000x reference)
//
#include <hip/hip_runtime.h>
#include <math.h>

// GRU(64 -> hidden=1), one timestep, per-row independent.
// rows = B*N = 524288, each row = [h, x0..x63] contiguous f32.

#define THREADS 128
#define RPB 128            // rows per block == threads
#define ROW_F 65           // floats per row
#define BLK_F (RPB * ROW_F)      // 8320 floats per block region
#define BLK_F4 (BLK_F / 4)       // 2080 float4 per block region

__device__ __forceinline__ float sigmoidf_(float v) {
    return 1.0f / (1.0f + __expf(-v));
}

__global__ __launch_bounds__(THREADS)
void gru_cell_kernel(const float* __restrict__ inputs,
                     const float* __restrict__ W_ih,   // [3][64] (r,z,n rows)
                     const float* __restrict__ W_hh,   // [3]
                     const float* __restrict__ b_ih,   // [3]
                     const float* __restrict__ b_hh,   // [3]
                     const float* __restrict__ w_out,  // [1]
                     const float* __restrict__ b_out,  // [1]
                     float* __restrict__ out,
                     int nrows)
{
    __shared__ float4 lds4[BLK_F4];   // 33280 B: 128 rows x 65 f32
    __shared__ float4 ldsW4[48];      // 768 B: W_ih 3x64

    const int tid = threadIdx.x;
    const int blk = blockIdx.x;

    // ---- stage 128 rows (contiguous 33280 B) via coalesced float4 ----
    const float4* src4 =
        reinterpret_cast<const float4*>(inputs + (size_t)blk * BLK_F);
    #pragma unroll
    for (int k = 0; k < (BLK_F4 + THREADS - 1) / THREADS; ++k) {
        int i = tid + k * THREADS;
        if (i < BLK_F4) lds4[i] = src4[i];
    }
    // ---- stage W_ih ----
    {
        float* ldsW = reinterpret_cast<float*>(ldsW4);
        for (int i = tid; i < 192; i += THREADS) ldsW[i] = W_ih[i];
    }
    __syncthreads();

    const int row_idx = blk * RPB + tid;
    if (row_idx >= nrows) return;

    const float* row = reinterpret_cast<const float*>(lds4) + tid * ROW_F;
    const float h = row[0];
    const float* x = row + 1;

    // ---- 3 dot products of length 64 ----
    float a0 = 0.0f, a1 = 0.0f, a2 = 0.0f;
    #pragma unroll
    for (int j4 = 0; j4 < 16; ++j4) {
        const float4 w0 = ldsW4[j4];        // gate r weights
        const float4 w1 = ldsW4[16 + j4];   // gate z weights
        const float4 w2 = ldsW4[32 + j4];   // gate n weights
        const float x0 = x[4 * j4 + 0];
        const float x1 = x[4 * j4 + 1];
        const float x2 = x[4 * j4 + 2];
        const float x3 = x[4 * j4 + 3];
        a0 = fmaf(x0, w0.x, a0); a0 = fmaf(x1, w0.y, a0);
        a0 = fmaf(x2, w0.z, a0); a0 = fmaf(x3, w0.w, a0);
        a1 = fmaf(x0, w1.x, a1); a1 = fmaf(x1, w1.y, a1);
        a1 = fmaf(x2, w1.z, a1); a1 = fmaf(x3, w1.w, a1);
        a2 = fmaf(x0, w2.x, a2); a2 = fmaf(x1, w2.y, a2);
        a2 = fmaf(x2, w2.z, a2); a2 = fmaf(x3, w2.w, a2);
    }

    // ---- gates (uniform scalar params: L1 broadcast) ----
    const float gh0 = fmaf(h, W_hh[0], b_hh[0]);
    const float gh1 = fmaf(h, W_hh[1], b_hh[1]);
    const float gh2 = fmaf(h, W_hh[2], b_hh[2]);

    const float r = sigmoidf_(a0 + b_ih[0] + gh0);
    const float z = sigmoidf_(a1 + b_ih[1] + gh1);
    const float n = tanhf(a2 + b_ih[2] + fmaf(r, gh2, 0.0f));
    const float h_new = (1.0f - z) * n + z * h;

    out[row_idx] = fmaf(h_new, w_out[0], b_out[0]);
}

extern "C" void kernel_launch(void* const* d_in, const int* in_sizes, int n_in,
                              void* d_out, int out_size, void* d_ws, size_t ws_size,
                              hipStream_t stream) {
    const float* inputs = (const float*)d_in[0];
    const float* W_ih   = (const float*)d_in[1];
    const float* W_hh   = (const float*)d_in[2];
    const float* b_ih   = (const float*)d_in[3];
    const float* b_hh   = (const float*)d_in[4];
    const float* w_out  = (const float*)d_in[5];
    const float* b_out  = (const float*)d_in[6];
    float* out = (float*)d_out;

    const int nrows = in_sizes[0] / ROW_F;          // 524288
    const int blocks = (nrows + RPB - 1) / RPB;     // 4096

    gru_cell_kernel<<<dim3(blocks), dim3(THREADS), 0, stream>>>(
        inputs, W_ih, W_hh, b_ih, b_hh, w_out, b_out, out, nrows);
}

// Round 3
// 26.708 us; speedup vs baseline: 1.3597x; 1.3597x over previous
//
#include <hip/hip_runtime.h>
#include <math.h>

// GRU(64 -> hidden=1), one timestep. rows = B*N = 524288,
// row = [h, x0..x63] contiguous f32 (65 floats = 260 B).
//
// Structure: single-wave blocks (64 threads, 64 rows each).
//  - 16x global_load_lds dwordx4 stages 16 KiB of the 16.64 KiB region
//    (direct HBM->LDS DMA, wave-uniform LDS base + lane*16).
//  - 256 B tail + W_ih (768 B) staged via regular copies.
//  - LDS/block = 16640 + 768 = 17408 B -> 9 blocks/CU, no cross-wave
//    barrier lockstep; 8192 independent blocks pipeline each other.

#define THREADS 64
#define RPB 64                    // rows per block
#define ROW_F 65                  // floats per row
#define REGION_F (RPB * ROW_F)    // 4160 floats = 16640 B per block
#define FULL_ITERS 16             // 16 x (64 lanes x 16 B) = 16384 B
#define TAIL_F4 16                // remaining 256 B = 16 float4

__device__ __forceinline__ float sigmoidf_(float v) {
    return 1.0f / (1.0f + __expf(-v));
}

__device__ __forceinline__ void async_copy16(const void* g, void* l) {
    __builtin_amdgcn_global_load_lds(
        (const __attribute__((address_space(1))) void*)g,
        (__attribute__((address_space(3))) void*)l,
        16, 0, 0);
}

__global__ __launch_bounds__(THREADS)
void gru_cell_kernel(const float* __restrict__ inputs,
                     const float* __restrict__ W_ih,   // [3][64]
                     const float* __restrict__ W_hh,   // [3]
                     const float* __restrict__ b_ih,   // [3]
                     const float* __restrict__ b_hh,   // [3]
                     const float* __restrict__ w_out,  // [1]
                     const float* __restrict__ b_out,  // [1]
                     float* __restrict__ out)
{
    __shared__ float  ldsRow[REGION_F];  // 16640 B
    __shared__ float4 ldsW4[48];         // 768 B (3x64 f32)

    const int lane = threadIdx.x;
    const size_t base = (size_t)blockIdx.x * REGION_F;
    const char* gsrc = (const char*)(inputs + base);

    // ---- async HBM -> LDS staging: 16 x dwordx4 per lane ----
    #pragma unroll
    for (int it = 0; it < FULL_ITERS; ++it) {
        async_copy16(gsrc + it * 1024 + lane * 16,
                     (char*)ldsRow + it * 1024);
    }
    // ---- 256 B tail (lanes 0..15) ----
    if (lane < TAIL_F4) {
        reinterpret_cast<float4*>(ldsRow)[FULL_ITERS * 64 + lane] =
            reinterpret_cast<const float4*>(gsrc)[FULL_ITERS * 64 + lane];
    }
    // ---- W_ih (lanes 0..47) ----
    if (lane < 48) {
        ldsW4[lane] = reinterpret_cast<const float4*>(W_ih)[lane];
    }

    __syncthreads();   // single wave: emits vmcnt(0)/lgkmcnt(0) drain + cheap barrier

    const float* row = ldsRow + lane * ROW_F;
    const float h = row[0];
    const float* x = row + 1;

    // ---- 3 dot products of length 64 (weights broadcast from LDS) ----
    float a0 = 0.0f, a1 = 0.0f, a2 = 0.0f;
    #pragma unroll
    for (int j4 = 0; j4 < 16; ++j4) {
        const float4 w0 = ldsW4[j4];
        const float4 w1 = ldsW4[16 + j4];
        const float4 w2 = ldsW4[32 + j4];
        const float x0 = x[4 * j4 + 0];
        const float x1 = x[4 * j4 + 1];
        const float x2 = x[4 * j4 + 2];
        const float x3 = x[4 * j4 + 3];
        a0 = fmaf(x0, w0.x, a0); a0 = fmaf(x1, w0.y, a0);
        a0 = fmaf(x2, w0.z, a0); a0 = fmaf(x3, w0.w, a0);
        a1 = fmaf(x0, w1.x, a1); a1 = fmaf(x1, w1.y, a1);
        a1 = fmaf(x2, w1.z, a1); a1 = fmaf(x3, w1.w, a1);
        a2 = fmaf(x0, w2.x, a2); a2 = fmaf(x1, w2.y, a2);
        a2 = fmaf(x2, w2.z, a2); a2 = fmaf(x3, w2.w, a2);
    }

    // ---- gates ----
    const float gh0 = fmaf(h, W_hh[0], b_hh[0]);
    const float gh1 = fmaf(h, W_hh[1], b_hh[1]);
    const float gh2 = fmaf(h, W_hh[2], b_hh[2]);

    const float r = sigmoidf_(a0 + b_ih[0] + gh0);
    const float z = sigmoidf_(a1 + b_ih[1] + gh1);
    const float n = tanhf(a2 + b_ih[2] + r * gh2);
    const float h_new = (1.0f - z) * n + z * h;

    out[(size_t)blockIdx.x * RPB + lane] = fmaf(h_new, w_out[0], b_out[0]);
}

extern "C" void kernel_launch(void* const* d_in, const int* in_sizes, int n_in,
                              void* d_out, int out_size, void* d_ws, size_t ws_size,
                              hipStream_t stream) {
    const float* inputs = (const float*)d_in[0];
    const float* W_ih   = (const float*)d_in[1];
    const float* W_hh   = (const float*)d_in[2];
    const float* b_ih   = (const float*)d_in[3];
    const float* b_hh   = (const float*)d_in[4];
    const float* w_out  = (const float*)d_in[5];
    const float* b_out  = (const float*)d_in[6];
    float* out = (float*)d_out;

    const int nrows  = in_sizes[0] / ROW_F;          // 524288
    const int blocks = nrows / RPB;                  // 8192 (exact)

    gru_cell_kernel<<<dim3(blocks), dim3(THREADS), 0, stream>>>(
        inputs, W_ih, W_hh, b_ih, b_hh, w_out, b_out, out);
}

// Round 4
// 26.208 us; speedup vs baseline: 1.3856x; 1.0190x over previous
//
#include <hip/hip_runtime.h>
#include <math.h>

// GRU(64 -> hidden=1), one timestep. rows = B*N = 524288,
// row = [h, x0..x63] contiguous f32 (65 floats = 260 B).
//
// Max-occupancy structure: 128-thread blocks, 32 rows/block,
// 4 lanes cooperate per row (quarter-row dot + shfl_xor reduce).
// LDS/block = 8320 B rows + 768 B weights ~ 9.1 KB -> ~16 blocks/CU
// = 32 waves/CU (vs 9 in R2). Staging via global_load_lds dwordx4.

#define THREADS 128
#define RPB 32                    // rows per block
#define ROW_F 65                  // floats per row
#define REGION_F (RPB * ROW_F)    // 2080 floats = 8320 B
#define REGION_B (REGION_F * 4)   // 8320 B
#define FULL_ITERS 4              // 4 x (128 threads x 16 B) = 8192 B
#define TAIL_F4 8                 // remaining 128 B = 8 float4

__device__ __forceinline__ float sigmoidf_(float v) {
    return 1.0f / (1.0f + __expf(-v));
}

__device__ __forceinline__ void async_copy16(const void* g, void* l) {
    __builtin_amdgcn_global_load_lds(
        (const __attribute__((address_space(1))) void*)g,
        (__attribute__((address_space(3))) void*)l,
        16, 0, 0);
}

__global__ __launch_bounds__(THREADS)
void gru_cell_kernel(const float* __restrict__ inputs,
                     const float* __restrict__ W_ih,   // [3][64]
                     const float* __restrict__ W_hh,   // [3]
                     const float* __restrict__ b_ih,   // [3]
                     const float* __restrict__ b_hh,   // [3]
                     const float* __restrict__ w_out,  // [1]
                     const float* __restrict__ b_out,  // [1]
                     float* __restrict__ out)
{
    __shared__ float ldsRow[REGION_F];  // 8320 B: 32 rows x 65 f32
    __shared__ float ldsW[192];         // 768 B: W_ih 3x64

    const int tid  = threadIdx.x;
    const size_t base = (size_t)blockIdx.x * REGION_F;
    const char* gsrc = (const char*)(inputs + base);

    // ---- async HBM -> LDS: per iter, each wave writes uniform-base+lane*16 ----
    const int wave_off = (tid >> 6) << 10;   // wave_id * 1024 B
    #pragma unroll
    for (int it = 0; it < FULL_ITERS; ++it) {
        async_copy16(gsrc + it * 2048 + tid * 16,
                     (char*)ldsRow + it * 2048 + wave_off);
    }
    // ---- 128 B tail (threads 0..7), manual copy ----
    if (tid < TAIL_F4) {
        reinterpret_cast<float4*>(ldsRow)[FULL_ITERS * 128 + tid] =
            reinterpret_cast<const float4*>(gsrc)[FULL_ITERS * 128 + tid];
    }
    // ---- W_ih (threads 0..47) ----
    if (tid < 48) {
        reinterpret_cast<float4*>(ldsW)[tid] =
            reinterpret_cast<const float4*>(W_ih)[tid];
    }

    __syncthreads();

    // ---- 4 lanes per row: lane q handles x[q*16 .. q*16+16) ----
    const int r = tid >> 2;          // row 0..31
    const int q = tid & 3;           // quarter 0..3
    const float* x  = ldsRow + r * ROW_F + 1 + q * 16;
    const float* w0 = ldsW +   0 + q * 16;
    const float* w1 = ldsW +  64 + q * 16;
    const float* w2 = ldsW + 128 + q * 16;

    float a0 = 0.0f, a1 = 0.0f, a2 = 0.0f;
    #pragma unroll
    for (int j = 0; j < 16; ++j) {
        const float xv = x[j];
        a0 = fmaf(xv, w0[j], a0);
        a1 = fmaf(xv, w1[j], a1);
        a2 = fmaf(xv, w2[j], a2);
    }

    // ---- reduce across the 4-lane group ----
    a0 += __shfl_xor(a0, 1); a0 += __shfl_xor(a0, 2);
    a1 += __shfl_xor(a1, 1); a1 += __shfl_xor(a1, 2);
    a2 += __shfl_xor(a2, 1); a2 += __shfl_xor(a2, 2);

    // ---- gates (all lanes compute; q==0 stores) ----
    const float h = ldsRow[r * ROW_F];
    const float gh0 = fmaf(h, W_hh[0], b_hh[0]);
    const float gh1 = fmaf(h, W_hh[1], b_hh[1]);
    const float gh2 = fmaf(h, W_hh[2], b_hh[2]);

    const float rg = sigmoidf_(a0 + b_ih[0] + gh0);
    const float zg = sigmoidf_(a1 + b_ih[1] + gh1);
    const float ng = tanhf(a2 + b_ih[2] + rg * gh2);
    const float h_new = (1.0f - zg) * ng + zg * h;

    if (q == 0) {
        out[(size_t)blockIdx.x * RPB + r] = fmaf(h_new, w_out[0], b_out[0]);
    }
}

extern "C" void kernel_launch(void* const* d_in, const int* in_sizes, int n_in,
                              void* d_out, int out_size, void* d_ws, size_t ws_size,
                              hipStream_t stream) {
    const float* inputs = (const float*)d_in[0];
    const float* W_ih   = (const float*)d_in[1];
    const float* W_hh   = (const float*)d_in[2];
    const float* b_ih   = (const float*)d_in[3];
    const float* b_hh   = (const float*)d_in[4];
    const float* w_out  = (const float*)d_in[5];
    const float* b_out  = (const float*)d_in[6];
    float* out = (float*)d_out;

    const int nrows  = in_sizes[0] / ROW_F;          // 524288
    const int blocks = nrows / RPB;                  // 16384 (exact)

    gru_cell_kernel<<<dim3(blocks), dim3(THREADS), 0, stream>>>(
        inputs, W_ih, W_hh, b_ih, b_hh, w_out, b_out, out);
}